// Round 7
// baseline (70.968 us; speedup 1.0000x reference)
//
#include <hip/hip_runtime.h>
#include <hip/hip_bf16.h>

#define B_ 8
#define S_ 2048
#define E_ 1024
#define H_ 64
#define LOG2E 1.4426950408889634f

typedef __attribute__((ext_vector_type(8))) short short8;
typedef __attribute__((ext_vector_type(4))) float floatx4;
typedef unsigned int u32;

static __device__ __forceinline__ short f2bf(float f) {
    union { float f; unsigned u; } a; a.f = f;
    unsigned r = a.u + 0x7FFF + ((a.u >> 16) & 1);
    return (short)(r >> 16);
}
static __device__ __forceinline__ float bf2f(short s) {
    union { unsigned u; float f; } a; a.u = ((u32)(unsigned short)s) << 16;
    return a.f;
}
static __device__ __forceinline__ void gl_lds16(const void* g, void* l) {
    __builtin_amdgcn_global_load_lds(
        (const __attribute__((address_space(1))) u32*)(g),
        (__attribute__((address_space(3))) u32*)(l),
        16, 0, 0);
}

// ---------------------------------------------------------------------------
// Kernel 1: weights -> bf16, tiled per K-panel [16][192][64] with XOR chunk
// swizzle pre-applied in global: element (ks,row,col) at
// ks*12288 + row*64 + ((col>>3)^(row&7))*8 + (col&7).
// ---------------------------------------------------------------------------
__global__ __launch_bounds__(256) void wprep_kernel(
        const float* __restrict__ wq, const float* __restrict__ wk,
        const float* __restrict__ wv, short* __restrict__ Wt) {
    __shared__ short Ws[64][73];
    int bid = blockIdx.x;            // 48 blocks: m = bid>>4, e-chunk = bid&15
    int m  = bid >> 4;
    int ec = bid & 15;
    const float* src = (m == 0) ? wq : ((m == 1) ? wk : wv);
    int t = threadIdx.x;
    {
        int er = t >> 2;
        int hc = (t & 3) * 16;
        const float* sp = src + (size_t)(ec * 64 + er) * H_ + hc;
        floatx4 v0 = *(const floatx4*)(sp);
        floatx4 v1 = *(const floatx4*)(sp + 4);
        floatx4 v2 = *(const floatx4*)(sp + 8);
        floatx4 v3 = *(const floatx4*)(sp + 12);
#pragma unroll
        for (int j = 0; j < 4; j++) Ws[er][hc + j]      = f2bf(v0[j]);
#pragma unroll
        for (int j = 0; j < 4; j++) Ws[er][hc + 4 + j]  = f2bf(v1[j]);
#pragma unroll
        for (int j = 0; j < 4; j++) Ws[er][hc + 8 + j]  = f2bf(v2[j]);
#pragma unroll
        for (int j = 0; j < 4; j++) Ws[er][hc + 12 + j] = f2bf(v3[j]);
    }
    __syncthreads();
    {
        int h  = t >> 2;
        int eo = (t & 3) * 16;
        int row = m * 64 + h;
        short* obase = Wt + (size_t)ec * 12288 + (size_t)row * 64;
#pragma unroll
        for (int g = 0; g < 2; g++) {
            short8 o;
#pragma unroll
            for (int jj = 0; jj < 8; jj++) o[jj] = Ws[eo + g * 8 + jj][h];
            int chunk = ((eo >> 3) + g) ^ (row & 7);
            *(short8*)(obase + chunk * 8) = o;
        }
    }
}

// ---------------------------------------------------------------------------
// Kernel 2: QKV projection GEMM, reg-staged write-late, DEPTH-2 PREFETCH.
// M=16384, K=1024, N=192, BM=32, BK=64, grid 512 (2 blocks/CU), 4 waves.
// Schedule per step s: compute(s) from LDS; ds_write stage(s+1) (its loads
// were issued ~2 steps ago -> HBM latency covered); issue loads(s+3);
// one barrier.  Unrolled x2 with named A/B stage regs (static indexing).
// ---------------------------------------------------------------------------
struct StageRegs {
    floatx4 x0, x1;
    short8 w0, w1, w2, w3, w4, w5;
};

__global__ __launch_bounds__(256) void qkv_proj_kernel(
        const float* __restrict__ x, const short* __restrict__ Wt,
        short* __restrict__ qb, short* __restrict__ kb, short* __restrict__ vb) {
    __shared__ __align__(16) short Wlds[2][12288];   // 2 x 24 KB
    __shared__ __align__(16) short Xlds[2][2304];    // 2 x 32*72 bf16 = 4.5 KB

    int tid  = threadIdx.x;
    int lane = tid & 63;
    int w    = tid >> 6;
    int lrow = lane & 15;
    int lgrp = lane >> 4;

    int wrow = (w >> 1) * 16;          // 0 / 16
    int wcol = (w & 1) * 96;           // 0 / 96
    int rowbase = blockIdx.x * 32;

    int xr = tid >> 3;                 // 0..31
    int xc = tid & 7;                  // 0..7 chunks of 8 floats
    const float* xgp = x + (size_t)(rowbase + xr) * E_ + xc * 8;
    const short* wgp = Wt + (size_t)w * 512 + lane * 8;

    floatx4 acc[6];
#pragma unroll
    for (int i = 0; i < 6; i++) acc[i] = (floatx4){0.f, 0.f, 0.f, 0.f};

    StageRegs A, B;

#define LOADST(R, KS) do {                                                   \
        const float* xn = xgp + (KS) * 64;                                   \
        R.x0 = *(const floatx4*)(xn);                                        \
        R.x1 = *(const floatx4*)(xn + 4);                                    \
        const short* wn = wgp + (size_t)(KS) * 12288;                        \
        R.w0 = *(const short8*)(wn);                                         \
        R.w1 = *(const short8*)(wn + 2048);                                  \
        R.w2 = *(const short8*)(wn + 4096);                                  \
        R.w3 = *(const short8*)(wn + 6144);                                  \
        R.w4 = *(const short8*)(wn + 8192);                                  \
        R.w5 = *(const short8*)(wn + 10240);                                 \
    } while (0)

#define WRITEST(R, BUF) do {                                                 \
        short8 xs;                                                           \
        xs[0] = f2bf(R.x0[0]); xs[1] = f2bf(R.x0[1]);                        \
        xs[2] = f2bf(R.x0[2]); xs[3] = f2bf(R.x0[3]);                        \
        xs[4] = f2bf(R.x1[0]); xs[5] = f2bf(R.x1[1]);                        \
        xs[6] = f2bf(R.x1[2]); xs[7] = f2bf(R.x1[3]);                        \
        *(short8*)&Xlds[BUF][xr * 72 + xc * 8] = xs;                         \
        short* lw = &Wlds[BUF][w * 512 + lane * 8];                          \
        *(short8*)(lw)         = R.w0;                                       \
        *(short8*)(lw + 2048)  = R.w1;                                       \
        *(short8*)(lw + 4096)  = R.w2;                                       \
        *(short8*)(lw + 6144)  = R.w3;                                       \
        *(short8*)(lw + 8192)  = R.w4;                                       \
        *(short8*)(lw + 10240) = R.w5;                                       \
    } while (0)

#define COMPUTE(BUF) do {                                                    \
        const short* xb = &Xlds[BUF][(wrow + lrow) * 72];                    \
        short8 a0 = *(const short8*)(xb + lgrp * 8);                         \
        short8 a1 = *(const short8*)(xb + 32 + lgrp * 8);                    \
        const short* wb = &Wlds[BUF][0];                                     \
        _Pragma("unroll")                                                    \
        for (int nf = 0; nf < 6; nf++) {                                     \
            int row = wcol + nf * 16 + lrow;                                 \
            int c0  = lgrp ^ (row & 7);                                      \
            short8 b0 = *(const short8*)(wb + row * 64 + c0 * 8);            \
            short8 b1 = *(const short8*)(wb + row * 64 + (c0 ^ 4) * 8);      \
            acc[nf] = __builtin_amdgcn_mfma_f32_16x16x32_bf16(a0, b0, acc[nf], 0, 0, 0); \
            acc[nf] = __builtin_amdgcn_mfma_f32_16x16x32_bf16(a1, b1, acc[nf], 0, 0, 0); \
        }                                                                    \
    } while (0)

    // ---- prologue: stage step 0; preload steps 1,2 ----
    LOADST(B, 0);
    WRITEST(B, 0);               // waits only on B's loads
    LOADST(A, 1);
    LOADST(B, 2);
    __syncthreads();

    // steps: even -> buf0, odd -> buf1.  A holds odd steps, B even steps.
    for (int i = 0; i < 16; i += 2) {
        COMPUTE(0);              // step i
        WRITEST(A, 1);           // stage step i+1 (loads issued ~2 steps ago)
        if (i + 3 < 16) LOADST(A, i + 3);
        __syncthreads();
        COMPUTE(1);              // step i+1
        if (i + 2 < 16) WRITEST(B, 0);
        if (i + 4 < 16) LOADST(B, i + 4);
        __syncthreads();
    }
#undef LOADST
#undef WRITEST
#undef COMPUTE

    // --- epilogue: transpose through LDS, coalesced short8 stores ---
    {
        short* sl = &Wlds[0][w * 1664];    // per-wave [16][104]
#pragma unroll
        for (int nf = 0; nf < 6; nf++)
#pragma unroll
            for (int j = 0; j < 4; j++)
                sl[(lgrp * 4 + j) * 104 + nf * 16 + lrow] = f2bf(acc[nf][j]);
        __syncthreads();
#pragma unroll
        for (int i = 0; i < 3; i++) {
            int mIdx = lane + 64 * i;          // 0..191 = 16 rows x 12 chunks
            int rloc = mIdx / 12;
            int cm   = mIdx % 12;
            short8 v = *(const short8*)(sl + rloc * 104 + cm * 8);
            int grow = rowbase + wrow + rloc;
            int gcol = wcol + cm * 8;
            short* dst = (gcol < 64) ? qb : ((gcol < 128) ? kb : vb);
            int cc = gcol & 63;
            *(short8*)(dst + (size_t)grow * H_ + cc) = v;
        }
    }
}

// ---------------------------------------------------------------------------
// Kernel 3: causal flash attention, split-KV (unchanged control).
// ---------------------------------------------------------------------------
__global__ __launch_bounds__(256) void attn_kernel(
        const short* __restrict__ qb, const short* __restrict__ kb,
        const short* __restrict__ vb, short* __restrict__ Opart,
        float* __restrict__ ml, int nsplit) {
    __shared__ __align__(16) short Klds[2][4096];   // 2 x 8 KB
    __shared__ __align__(16) short Vt[64][72];      // V^T [h][kv], padded
    __shared__ __align__(16) short Ps[4][16][72];   // per-wave P (and O) tile

    int tid  = threadIdx.x;
    int lane = tid & 63;
    int w    = tid >> 6;
    int lrow = lane & 15;
    int lgrp = lane >> 4;
    int lk   = lgrp * 8;

    int sp = blockIdx.x % nsplit;
    int bq = blockIdx.x / nsplit;
    int qt = bq & 31;
    int b  = bq >> 5;
    int q0 = qt * 64;

    int T = qt + 1;
    int chunk = (T + nsplit - 1) / nsplit;
    int t0 = sp * chunk;
    int t1 = (T < t0 + chunk) ? T : (t0 + chunk);

    size_t mlrow = (size_t)sp * 16384 + (size_t)b * S_ + q0 + w * 16 + lgrp * 4;

    if (t0 >= T) {
        if (lrow == 0) {
#pragma unroll
            for (int j = 0; j < 4; j++) {
                ml[(mlrow + j) * 2 + 0] = -1e30f;
                ml[(mlrow + j) * 2 + 1] = 0.f;
            }
        }
        return;
    }

    const short* kbase = kb + (size_t)b * S_ * H_;
    const short* vbase = vb + (size_t)b * S_ * H_;

    int qrow = q0 + w * 16 + lrow;
    const short* qptr = qb + ((size_t)b * S_ + qrow) * H_;
    short8 qf0 = *(const short8*)(qptr + lk);
    short8 qf1 = *(const short8*)(qptr + 32 + lk);

#define STAGE_K(TT, BUF) do {                                                 \
        int kv0s = (TT) * 64;                                                 \
        _Pragma("unroll")                                                     \
        for (int it = 0; it < 2; it++) {                                      \
            int j = it * 256 + w * 64 + lane;                                 \
            int r = j >> 3; int c = j & 7;                                    \
            const short* pk = kbase + (size_t)(kv0s + r) * H_ +               \
                              ((c ^ (r & 7)) << 3);                           \
            short* lkp = &Klds[BUF][(it * 256 + w * 64) * 8];                 \
            gl_lds16(pk, lkp);                                                \
        } } while (0)

    int kvr = tid >> 2;
    int hs  = (tid & 3) * 16;

    STAGE_K(t0, 0);
    const short* vp0 = vbase + (size_t)(t0 * 64 + kvr) * H_ + hs;
    short8 vr0 = *(const short8*)vp0;
    short8 vr1 = *(const short8*)(vp0 + 8);

    floatx4 O[4];
#pragma unroll
    for (int nf = 0; nf < 4; nf++) O[nf] = (floatx4){0.f, 0.f, 0.f, 0.f};
    float m[4], lsum[4];
#pragma unroll
    for (int j = 0; j < 4; j++) { m[j] = -1e30f; lsum[j] = 0.f; }

    for (int t = t0; t < t1; t++) {
        int cur = (t - t0) & 1;
        int kv0 = t * 64;
        __syncthreads();                 // K(t) staged; Vt/Ps free

        if (t + 1 < t1) STAGE_K(t + 1, cur ^ 1);

        // write V(t) from regs (transposed)
#pragma unroll
        for (int c = 0; c < 8; c++) Vt[hs + c][kvr] = vr0[c];
#pragma unroll
        for (int c = 0; c < 8; c++) Vt[hs + 8 + c][kvr] = vr1[c];

        // prefetch V(t+1)
        if (t + 1 < t1) {
            const short* vp = vbase + (size_t)((t + 1) * 64 + kvr) * H_ + hs;
            vr0 = *(const short8*)vp;
            vr1 = *(const short8*)(vp + 8);
        }

        // --- S = (Q K^T) * scale, K frags from swizzled LDS ---
        floatx4 s[4];
#pragma unroll
        for (int nf = 0; nf < 4; nf++) {
            int r = nf * 16 + lrow;
            int c0 = lgrp ^ (r & 7);
            const short* kp = &Klds[cur][r * 64];
            short8 b0 = *(const short8*)(kp + c0 * 8);
            short8 b1 = *(const short8*)(kp + (c0 ^ 4) * 8);
            floatx4 a = (floatx4){0.f, 0.f, 0.f, 0.f};
            a = __builtin_amdgcn_mfma_f32_16x16x32_bf16(qf0, b0, a, 0, 0, 0);
            a = __builtin_amdgcn_mfma_f32_16x16x32_bf16(qf1, b1, a, 0, 0, 0);
            s[nf] = a;
        }
#pragma unroll
        for (int nf = 0; nf < 4; nf++)
#pragma unroll
            for (int j = 0; j < 4; j++) s[nf][j] *= 0.03125f;

        if (t == qt) {
#pragma unroll
            for (int nf = 0; nf < 4; nf++) {
                int kvidx = kv0 + nf * 16 + lrow;
#pragma unroll
                for (int j = 0; j < 4; j++) {
                    int qidx = q0 + w * 16 + lgrp * 4 + j;
                    if (kvidx > qidx) s[nf][j] = -1e30f;
                }
            }
        }

        float alpha[4];
#pragma unroll
        for (int j = 0; j < 4; j++) {
            float mx = fmaxf(fmaxf(s[0][j], s[1][j]), fmaxf(s[2][j], s[3][j]));
#pragma unroll
            for (int off = 1; off < 16; off <<= 1)
                mx = fmaxf(mx, __shfl_xor(mx, off));
            float mn = fmaxf(m[j], mx);
            alpha[j] = exp2f((m[j] - mn) * LOG2E);
            m[j] = mn;
            float ps = 0.f;
#pragma unroll
            for (int nf = 0; nf < 4; nf++) {
                float p = exp2f((s[nf][j] - mn) * LOG2E);
                s[nf][j] = p;
                ps += p;
            }
#pragma unroll
            for (int off = 1; off < 16; off <<= 1)
                ps += __shfl_xor(ps, off);
            lsum[j] = lsum[j] * alpha[j] + ps;
        }

#pragma unroll
        for (int nf = 0; nf < 4; nf++) {
#pragma unroll
            for (int j = 0; j < 4; j++) {
                Ps[w][lgrp * 4 + j][nf * 16 + lrow] = f2bf(s[nf][j]);
                O[nf][j] *= alpha[j];
            }
        }
        __syncthreads();                 // Ps + Vt visible

        short8 pa0 = *(const short8*)&Ps[w][lrow][lk];
        short8 pa1 = *(const short8*)&Ps[w][lrow][32 + lk];
#pragma unroll
        for (int nf = 0; nf < 4; nf++) {
            short8 vb0 = *(const short8*)&Vt[nf * 16 + lrow][lk];
            short8 vb1 = *(const short8*)&Vt[nf * 16 + lrow][32 + lk];
            O[nf] = __builtin_amdgcn_mfma_f32_16x16x32_bf16(pa0, vb0, O[nf], 0, 0, 0);
            O[nf] = __builtin_amdgcn_mfma_f32_16x16x32_bf16(pa1, vb1, O[nf], 0, 0, 0);
        }
    }
#undef STAGE_K

    // --- epilogue: m,l + transposed coalesced bf16 O stores ---
    if (lrow == 0) {
#pragma unroll
        for (int j = 0; j < 4; j++) {
            ml[(mlrow + j) * 2 + 0] = m[j];
            ml[(mlrow + j) * 2 + 1] = lsum[j];
        }
    }
    __syncthreads();                     // all PV reads of Ps done
#pragma unroll
    for (int nf = 0; nf < 4; nf++)
#pragma unroll
        for (int j = 0; j < 4; j++)
            Ps[w][lgrp * 4 + j][nf * 16 + lrow] = f2bf(O[nf][j]);
    __syncthreads();
    {
        // full 16x64 coverage: 16 rows x 4 lane-chunks x 16 cols
        int row = lane >> 2;
        int c   = lane & 3;
        short8 ov0 = *(const short8*)&Ps[w][row][c * 16];
        short8 ov1 = *(const short8*)&Ps[w][row][c * 16 + 8];
        size_t grow = (size_t)sp * 16384 + (size_t)b * S_ + q0 + w * 16 + row;
        *(short8*)(Opart + grow * H_ + c * 16) = ov0;
        *(short8*)(Opart + grow * H_ + c * 16 + 8) = ov1;
    }
}

// ---------------------------------------------------------------------------
// Kernel 4: combine split partials (bf16 partial O), ACTIVE splits only.
// ---------------------------------------------------------------------------
__global__ __launch_bounds__(256) void combine_kernel(
        const short* __restrict__ Opart, const float* __restrict__ ml,
        float* __restrict__ out, int nsplit) {
    int t = threadIdx.x;
    int row = blockIdx.x * 4 + (t >> 6);   // 0..16383
    int h = t & 63;

    // active split count for this row's q-tile (mirrors attn's chunking)
    int q = row & (S_ - 1);
    int T = (q >> 6) + 1;
    int chunk = (T + nsplit - 1) / nsplit;
    int nact = (T + chunk - 1) / chunk;

    float M = -1e30f;
    for (int s = 0; s < nact; s++)
        M = fmaxf(M, ml[((size_t)s * 16384 + row) * 2]);

    float L = 0.f, acc = 0.f;
    for (int s = 0; s < nact; s++) {
        float ms = ml[((size_t)s * 16384 + row) * 2];
        float ls = ml[((size_t)s * 16384 + row) * 2 + 1];
        float wgt = exp2f((ms - M) * LOG2E);
        L += wgt * ls;
        acc += wgt * bf2f(Opart[((size_t)s * 16384 + row) * H_ + h]);
    }
    out[(size_t)row * H_ + h] = acc / L;
}

// ---------------------------------------------------------------------------
extern "C" void kernel_launch(void* const* d_in, const int* in_sizes, int n_in,
                              void* d_out, int out_size, void* d_ws, size_t ws_size,
                              hipStream_t stream) {
    const float* x  = (const float*)d_in[0];
    const float* wq = (const float*)d_in[1];
    const float* wk = (const float*)d_in[2];
    const float* wv = (const float*)d_in[3];
    float* out = (float*)d_out;

    char* ws = (char*)d_ws;
    const size_t WT_BYTES  = (size_t)192 * 1024 * 2;            // 384 KB
    const size_t QKV_BYTES = (size_t)B_ * S_ * H_ * 2;          // 2 MB each
    const size_t ML_BYTES  = (size_t)8 * 16384 * 2 * 4;         // 1 MB (8 splits)
    const size_t OP_UNIT   = (size_t)16384 * H_ * 2;            // 2 MB per split (bf16)

    short* Wt = (short*)ws;
    short* qb = (short*)(ws + WT_BYTES);
    short* kb = (short*)(ws + WT_BYTES + QKV_BYTES);
    short* vb = (short*)(ws + WT_BYTES + 2 * QKV_BYTES);
    char*  mlp = ws + WT_BYTES + 3 * QKV_BYTES;
    char*  opp = mlp + ML_BYTES;
    size_t fixed = WT_BYTES + 3 * QKV_BYTES + ML_BYTES;

    int nsplit = 1;
    if (ws_size >= fixed + 8 * OP_UNIT) nsplit = 8;
    else if (ws_size >= fixed + 4 * OP_UNIT) nsplit = 4;
    else if (ws_size >= fixed + 2 * OP_UNIT) nsplit = 2;

    wprep_kernel<<<48, 256, 0, stream>>>(wq, wk, wv, Wt);
    qkv_proj_kernel<<<512, 256, 0, stream>>>(x, Wt, qb, kb, vb);
    attn_kernel<<<8 * 32 * nsplit, 256, 0, stream>>>(qb, kb, vb,
            (short*)opp, (float*)mlp, nsplit);
    combine_kernel<<<4096, 256, 0, stream>>>((const short*)opp,
            (const float*)mlp, out, nsplit);
}

// Round 9
// 69.912 us; speedup vs baseline: 1.0151x; 1.0151x over previous
//
#include <hip/hip_runtime.h>
#include <hip/hip_bf16.h>

#define B_ 8
#define S_ 2048
#define E_ 1024
#define H_ 64
#define LOG2E 1.4426950408889634f

typedef __attribute__((ext_vector_type(8))) short short8;
typedef __attribute__((ext_vector_type(4))) short bf16x4;
typedef __attribute__((ext_vector_type(4))) float floatx4;
typedef unsigned int u32;

static __device__ __forceinline__ short f2bf(float f) {
    union { float f; unsigned u; } a; a.f = f;
    unsigned r = a.u + 0x7FFF + ((a.u >> 16) & 1);
    return (short)(r >> 16);
}
static __device__ __forceinline__ float bf2f(short s) {
    union { unsigned u; float f; } a; a.u = ((u32)(unsigned short)s) << 16;
    return a.f;
}
static __device__ __forceinline__ void gl_lds16(const void* g, void* l) {
    __builtin_amdgcn_global_load_lds(
        (const __attribute__((address_space(1))) u32*)(g),
        (__attribute__((address_space(3))) u32*)(l),
        16, 0, 0);
}

// ---------------------------------------------------------------------------
// Kernel 1: weights -> bf16, tiled per K-panel [16][192][64] with XOR chunk
// swizzle pre-applied in global: element (ks,row,col) at
// ks*12288 + row*64 + ((col>>3)^(row&7))*8 + (col&7).
// ---------------------------------------------------------------------------
__global__ __launch_bounds__(256) void wprep_kernel(
        const float* __restrict__ wq, const float* __restrict__ wk,
        const float* __restrict__ wv, short* __restrict__ Wt) {
    __shared__ short Ws[64][73];
    int bid = blockIdx.x;            // 48 blocks: m = bid>>4, e-chunk = bid&15
    int m  = bid >> 4;
    int ec = bid & 15;
    const float* src = (m == 0) ? wq : ((m == 1) ? wk : wv);
    int t = threadIdx.x;
    {
        int er = t >> 2;
        int hc = (t & 3) * 16;
        const float* sp = src + (size_t)(ec * 64 + er) * H_ + hc;
        floatx4 v0 = *(const floatx4*)(sp);
        floatx4 v1 = *(const floatx4*)(sp + 4);
        floatx4 v2 = *(const floatx4*)(sp + 8);
        floatx4 v3 = *(const floatx4*)(sp + 12);
#pragma unroll
        for (int j = 0; j < 4; j++) Ws[er][hc + j]      = f2bf(v0[j]);
#pragma unroll
        for (int j = 0; j < 4; j++) Ws[er][hc + 4 + j]  = f2bf(v1[j]);
#pragma unroll
        for (int j = 0; j < 4; j++) Ws[er][hc + 8 + j]  = f2bf(v2[j]);
#pragma unroll
        for (int j = 0; j < 4; j++) Ws[er][hc + 12 + j] = f2bf(v3[j]);
    }
    __syncthreads();
    {
        int h  = t >> 2;
        int eo = (t & 3) * 16;
        int row = m * 64 + h;
        short* obase = Wt + (size_t)ec * 12288 + (size_t)row * 64;
#pragma unroll
        for (int g = 0; g < 2; g++) {
            short8 o;
#pragma unroll
            for (int jj = 0; jj < 8; jj++) o[jj] = Ws[eo + g * 8 + jj][h];
            int chunk = ((eo >> 3) + g) ^ (row & 7);
            *(short8*)(obase + chunk * 8) = o;
        }
    }
}

// ---------------------------------------------------------------------------
// Kernel 2: QKV projection GEMM, 8-WAVE blocks for 4 waves/SIMD.
// M=16384, K=1024, N=192, BM=32, BK=64.  512 blocks x 512 thr; 2 blocks/CU
// (LDS 57 KB), 16 waves/CU.  Wave tile = 16 rows x 48 cols (3 accs).
// Depth-1 reg-staged write-late schedule.
// ---------------------------------------------------------------------------
struct StageRegs {
    floatx4 x0;
    short8 w0, w1, w2;
};

__global__ __launch_bounds__(512, 4) void qkv_proj_kernel(
        const float* __restrict__ x, const short* __restrict__ Wt,
        short* __restrict__ qb, short* __restrict__ kb, short* __restrict__ vb) {
    __shared__ __align__(16) short Wlds[2][12288];   // 2 x 24 KB
    __shared__ __align__(16) short Xlds[2][2304];    // 2 x 32*72 bf16 = 4.5 KB

    int tid  = threadIdx.x;
    int lane = tid & 63;
    int w    = tid >> 6;               // 0..7
    int lrow = lane & 15;
    int lgrp = lane >> 4;

    int wr = w >> 2;                   // 0/1 : rows wr*16..+16
    int wc = w & 3;                    // 0..3: cols wc*48..+48
    int rowbase = blockIdx.x * 32;

    // staging mappings
    int xr  = tid >> 4;                // 0..31 (x row)
    int xc4 = tid & 15;                // 16 chunks of 4 floats
    const float* xgp = x + (size_t)(rowbase + xr) * E_ + xc4 * 4;
    const short* wgp = Wt + (size_t)tid * 8;

    floatx4 acc[3];
#pragma unroll
    for (int i = 0; i < 3; i++) acc[i] = (floatx4){0.f, 0.f, 0.f, 0.f};

    StageRegs A, B;

#define LOADST(R, KS) do {                                                   \
        R.x0 = *(const floatx4*)(xgp + (KS) * 64);                           \
        const short* wn = wgp + (size_t)(KS) * 12288;                        \
        R.w0 = *(const short8*)(wn);                                         \
        R.w1 = *(const short8*)(wn + 4096);                                  \
        R.w2 = *(const short8*)(wn + 8192);                                  \
    } while (0)

#define WRITEST(R, BUF) do {                                                 \
        bf16x4 xs;                                                           \
        xs[0] = f2bf(R.x0[0]); xs[1] = f2bf(R.x0[1]);                        \
        xs[2] = f2bf(R.x0[2]); xs[3] = f2bf(R.x0[3]);                        \
        *(bf16x4*)&Xlds[BUF][xr * 72 + xc4 * 4] = xs;                        \
        short* lw = &Wlds[BUF][tid * 8];                                     \
        *(short8*)(lw)        = R.w0;                                        \
        *(short8*)(lw + 4096) = R.w1;                                        \
        *(short8*)(lw + 8192) = R.w2;                                        \
    } while (0)

#define COMPUTE(BUF) do {                                                    \
        const short* xb = &Xlds[BUF][(wr * 16 + lrow) * 72];                 \
        short8 a0 = *(const short8*)(xb + lgrp * 8);                         \
        short8 a1 = *(const short8*)(xb + 32 + lgrp * 8);                    \
        const short* wb = &Wlds[BUF][0];                                     \
        _Pragma("unroll")                                                    \
        for (int nf = 0; nf < 3; nf++) {                                     \
            int row = wc * 48 + nf * 16 + lrow;                              \
            int c0  = lgrp ^ (row & 7);                                      \
            short8 b0 = *(const short8*)(wb + row * 64 + c0 * 8);            \
            short8 b1 = *(const short8*)(wb + row * 64 + (c0 ^ 4) * 8);      \
            acc[nf] = __builtin_amdgcn_mfma_f32_16x16x32_bf16(a0, b0, acc[nf], 0, 0, 0); \
            acc[nf] = __builtin_amdgcn_mfma_f32_16x16x32_bf16(a1, b1, acc[nf], 0, 0, 0); \
        }                                                                    \
    } while (0)

    // ---- prologue ----
    LOADST(B, 0);
    WRITEST(B, 0);
    LOADST(A, 1);
    __syncthreads();

    for (int i = 0; i < 16; i += 2) {
        COMPUTE(0);                      // step i
        WRITEST(A, 1);                   // stage i+1
        if (i + 2 < 16) LOADST(B, i + 2);
        __syncthreads();
        COMPUTE(1);                      // step i+1
        if (i + 2 < 16) WRITEST(B, 0);   // stage i+2
        if (i + 3 < 16) LOADST(A, i + 3);
        __syncthreads();
    }
#undef LOADST
#undef WRITEST
#undef COMPUTE

    // --- epilogue: per-wave slab transpose in Wlds[0], coalesced stores ---
    {
        short* sl = &Wlds[0][w * 1024];   // per-wave [16][64]
#pragma unroll
        for (int nf = 0; nf < 3; nf++)
#pragma unroll
            for (int j = 0; j < 4; j++)
                sl[(lgrp * 4 + j) * 64 + nf * 16 + lrow] = f2bf(acc[nf][j]);
        __syncthreads();
#pragma unroll
        for (int k = 0; k < 2; k++) {
            int id = tid + k * 512;           // 0..767 = 32 rows x 24 chunks
            if (id < 768) {
                int R  = id / 24;
                int cc = id % 24;
                int wv_ = (R >> 4) * 4 + cc / 6;
                short8 v = *(const short8*)&Wlds[0][wv_ * 1024 +
                                                    (R & 15) * 64 + (cc % 6) * 8];
                int gcol = cc * 8;
                short* dst = (gcol < 64) ? qb : ((gcol < 128) ? kb : vb);
                *(short8*)(dst + (size_t)(rowbase + R) * H_ + (gcol & 63)) = v;
            }
        }
    }
}

// ---------------------------------------------------------------------------
// Kernel 3: causal flash attention, split-KV (unchanged control).
// ---------------------------------------------------------------------------
__global__ __launch_bounds__(256) void attn_kernel(
        const short* __restrict__ qb, const short* __restrict__ kb,
        const short* __restrict__ vb, short* __restrict__ Opart,
        float* __restrict__ ml, int nsplit) {
    __shared__ __align__(16) short Klds[2][4096];   // 2 x 8 KB
    __shared__ __align__(16) short Vt[64][72];      // V^T [h][kv], padded
    __shared__ __align__(16) short Ps[4][16][72];   // per-wave P (and O) tile

    int tid  = threadIdx.x;
    int lane = tid & 63;
    int w    = tid >> 6;
    int lrow = lane & 15;
    int lgrp = lane >> 4;
    int lk   = lgrp * 8;

    int sp = blockIdx.x % nsplit;
    int bq = blockIdx.x / nsplit;
    int qt = bq & 31;
    int b  = bq >> 5;
    int q0 = qt * 64;

    int T = qt + 1;
    int chunk = (T + nsplit - 1) / nsplit;
    int t0 = sp * chunk;
    int t1 = (T < t0 + chunk) ? T : (t0 + chunk);

    size_t mlrow = (size_t)sp * 16384 + (size_t)b * S_ + q0 + w * 16 + lgrp * 4;

    if (t0 >= T) {
        if (lrow == 0) {
#pragma unroll
            for (int j = 0; j < 4; j++) {
                ml[(mlrow + j) * 2 + 0] = -1e30f;
                ml[(mlrow + j) * 2 + 1] = 0.f;
            }
        }
        return;
    }

    const short* kbase = kb + (size_t)b * S_ * H_;
    const short* vbase = vb + (size_t)b * S_ * H_;

    int qrow = q0 + w * 16 + lrow;
    const short* qptr = qb + ((size_t)b * S_ + qrow) * H_;
    short8 qf0 = *(const short8*)(qptr + lk);
    short8 qf1 = *(const short8*)(qptr + 32 + lk);

#define STAGE_K(TT, BUF) do {                                                 \
        int kv0s = (TT) * 64;                                                 \
        _Pragma("unroll")                                                     \
        for (int it = 0; it < 2; it++) {                                      \
            int j = it * 256 + w * 64 + lane;                                 \
            int r = j >> 3; int c = j & 7;                                    \
            const short* pk = kbase + (size_t)(kv0s + r) * H_ +               \
                              ((c ^ (r & 7)) << 3);                           \
            short* lkp = &Klds[BUF][(it * 256 + w * 64) * 8];                 \
            gl_lds16(pk, lkp);                                                \
        } } while (0)

    int kvr = tid >> 2;
    int hs  = (tid & 3) * 16;

    STAGE_K(t0, 0);
    const short* vp0 = vbase + (size_t)(t0 * 64 + kvr) * H_ + hs;
    short8 vr0 = *(const short8*)vp0;
    short8 vr1 = *(const short8*)(vp0 + 8);

    floatx4 O[4];
#pragma unroll
    for (int nf = 0; nf < 4; nf++) O[nf] = (floatx4){0.f, 0.f, 0.f, 0.f};
    float m[4], lsum[4];
#pragma unroll
    for (int j = 0; j < 4; j++) { m[j] = -1e30f; lsum[j] = 0.f; }

    for (int t = t0; t < t1; t++) {
        int cur = (t - t0) & 1;
        int kv0 = t * 64;
        __syncthreads();                 // K(t) staged; Vt/Ps free

        if (t + 1 < t1) STAGE_K(t + 1, cur ^ 1);

        // write V(t) from regs (transposed)
#pragma unroll
        for (int c = 0; c < 8; c++) Vt[hs + c][kvr] = vr0[c];
#pragma unroll
        for (int c = 0; c < 8; c++) Vt[hs + 8 + c][kvr] = vr1[c];

        // prefetch V(t+1)
        if (t + 1 < t1) {
            const short* vp = vbase + (size_t)((t + 1) * 64 + kvr) * H_ + hs;
            vr0 = *(const short8*)vp;
            vr1 = *(const short8*)(vp + 8);
        }

        // --- S = (Q K^T) * scale, K frags from swizzled LDS ---
        floatx4 s[4];
#pragma unroll
        for (int nf = 0; nf < 4; nf++) {
            int r = nf * 16 + lrow;
            int c0 = lgrp ^ (r & 7);
            const short* kp = &Klds[cur][r * 64];
            short8 b0 = *(const short8*)(kp + c0 * 8);
            short8 b1 = *(const short8*)(kp + (c0 ^ 4) * 8);
            floatx4 a = (floatx4){0.f, 0.f, 0.f, 0.f};
            a = __builtin_amdgcn_mfma_f32_16x16x32_bf16(qf0, b0, a, 0, 0, 0);
            a = __builtin_amdgcn_mfma_f32_16x16x32_bf16(qf1, b1, a, 0, 0, 0);
            s[nf] = a;
        }
#pragma unroll
        for (int nf = 0; nf < 4; nf++)
#pragma unroll
            for (int j = 0; j < 4; j++) s[nf][j] *= 0.03125f;

        if (t == qt) {
#pragma unroll
            for (int nf = 0; nf < 4; nf++) {
                int kvidx = kv0 + nf * 16 + lrow;
#pragma unroll
                for (int j = 0; j < 4; j++) {
                    int qidx = q0 + w * 16 + lgrp * 4 + j;
                    if (kvidx > qidx) s[nf][j] = -1e30f;
                }
            }
        }

        float alpha[4];
#pragma unroll
        for (int j = 0; j < 4; j++) {
            float mx = fmaxf(fmaxf(s[0][j], s[1][j]), fmaxf(s[2][j], s[3][j]));
#pragma unroll
            for (int off = 1; off < 16; off <<= 1)
                mx = fmaxf(mx, __shfl_xor(mx, off));
            float mn = fmaxf(m[j], mx);
            alpha[j] = exp2f((m[j] - mn) * LOG2E);
            m[j] = mn;
            float ps = 0.f;
#pragma unroll
            for (int nf = 0; nf < 4; nf++) {
                float p = exp2f((s[nf][j] - mn) * LOG2E);
                s[nf][j] = p;
                ps += p;
            }
#pragma unroll
            for (int off = 1; off < 16; off <<= 1)
                ps += __shfl_xor(ps, off);
            lsum[j] = lsum[j] * alpha[j] + ps;
        }

#pragma unroll
        for (int nf = 0; nf < 4; nf++) {
#pragma unroll
            for (int j = 0; j < 4; j++) {
                Ps[w][lgrp * 4 + j][nf * 16 + lrow] = f2bf(s[nf][j]);
                O[nf][j] *= alpha[j];
            }
        }
        __syncthreads();                 // Ps + Vt visible

        short8 pa0 = *(const short8*)&Ps[w][lrow][lk];
        short8 pa1 = *(const short8*)&Ps[w][lrow][32 + lk];
#pragma unroll
        for (int nf = 0; nf < 4; nf++) {
            short8 vb0 = *(const short8*)&Vt[nf * 16 + lrow][lk];
            short8 vb1 = *(const short8*)&Vt[nf * 16 + lrow][32 + lk];
            O[nf] = __builtin_amdgcn_mfma_f32_16x16x32_bf16(pa0, vb0, O[nf], 0, 0, 0);
            O[nf] = __builtin_amdgcn_mfma_f32_16x16x32_bf16(pa1, vb1, O[nf], 0, 0, 0);
        }
    }
#undef STAGE_K

    // --- epilogue: m,l + transposed coalesced bf16 O stores ---
    if (lrow == 0) {
#pragma unroll
        for (int j = 0; j < 4; j++) {
            ml[(mlrow + j) * 2 + 0] = m[j];
            ml[(mlrow + j) * 2 + 1] = lsum[j];
        }
    }
    __syncthreads();                     // all PV reads of Ps done
#pragma unroll
    for (int nf = 0; nf < 4; nf++)
#pragma unroll
        for (int j = 0; j < 4; j++)
            Ps[w][lgrp * 4 + j][nf * 16 + lrow] = f2bf(O[nf][j]);
    __syncthreads();
    {
        // full 16x64 coverage: 16 rows x 4 lane-chunks x 16 cols
        int row = lane >> 2;
        int c   = lane & 3;
        short8 ov0 = *(const short8*)&Ps[w][row][c * 16];
        short8 ov1 = *(const short8*)&Ps[w][row][c * 16 + 8];
        size_t grow = (size_t)sp * 16384 + (size_t)b * S_ + q0 + w * 16 + row;
        *(short8*)(Opart + grow * H_ + c * 16) = ov0;
        *(short8*)(Opart + grow * H_ + c * 16 + 8) = ov1;
    }
}

// ---------------------------------------------------------------------------
// Kernel 4: combine split partials (bf16 partial O), ACTIVE splits only.
// ---------------------------------------------------------------------------
__global__ __launch_bounds__(256) void combine_kernel(
        const short* __restrict__ Opart, const float* __restrict__ ml,
        float* __restrict__ out, int nsplit) {
    int t = threadIdx.x;
    int row = blockIdx.x * 4 + (t >> 6);   // 0..16383
    int h = t & 63;

    int q = row & (S_ - 1);
    int T = (q >> 6) + 1;
    int chunk = (T + nsplit - 1) / nsplit;
    int nact = (T + chunk - 1) / chunk;

    float M = -1e30f;
    for (int s = 0; s < nact; s++)
        M = fmaxf(M, ml[((size_t)s * 16384 + row) * 2]);

    float L = 0.f, acc = 0.f;
    for (int s = 0; s < nact; s++) {
        float ms = ml[((size_t)s * 16384 + row) * 2];
        float ls = ml[((size_t)s * 16384 + row) * 2 + 1];
        float wgt = exp2f((ms - M) * LOG2E);
        L += wgt * ls;
        acc += wgt * bf2f(Opart[((size_t)s * 16384 + row) * H_ + h]);
    }
    out[(size_t)row * H_ + h] = acc / L;
}

// ---------------------------------------------------------------------------
extern "C" void kernel_launch(void* const* d_in, const int* in_sizes, int n_in,
                              void* d_out, int out_size, void* d_ws, size_t ws_size,
                              hipStream_t stream) {
    const float* x  = (const float*)d_in[0];
    const float* wq = (const float*)d_in[1];
    const float* wk = (const float*)d_in[2];
    const float* wv = (const float*)d_in[3];
    float* out = (float*)d_out;

    char* ws = (char*)d_ws;
    const size_t WT_BYTES  = (size_t)192 * 1024 * 2;            // 384 KB
    const size_t QKV_BYTES = (size_t)B_ * S_ * H_ * 2;          // 2 MB each
    const size_t ML_BYTES  = (size_t)8 * 16384 * 2 * 4;         // 1 MB (8 splits)
    const size_t OP_UNIT   = (size_t)16384 * H_ * 2;            // 2 MB per split (bf16)

    short* Wt = (short*)ws;
    short* qb = (short*)(ws + WT_BYTES);
    short* kb = (short*)(ws + WT_BYTES + QKV_BYTES);
    short* vb = (short*)(ws + WT_BYTES + 2 * QKV_BYTES);
    char*  mlp = ws + WT_BYTES + 3 * QKV_BYTES;
    char*  opp = mlp + ML_BYTES;
    size_t fixed = WT_BYTES + 3 * QKV_BYTES + ML_BYTES;

    int nsplit = 1;
    if (ws_size >= fixed + 8 * OP_UNIT) nsplit = 8;
    else if (ws_size >= fixed + 4 * OP_UNIT) nsplit = 4;
    else if (ws_size >= fixed + 2 * OP_UNIT) nsplit = 2;

    wprep_kernel<<<48, 256, 0, stream>>>(wq, wk, wv, Wt);
    qkv_proj_kernel<<<512, 512, 0, stream>>>(x, Wt, qb, kb, vb);
    attn_kernel<<<8 * 32 * nsplit, 256, 0, stream>>>(qb, kb, vb,
            (short*)opp, (float*)mlp, nsplit);
    combine_kernel<<<4096, 256, 0, stream>>>((const short*)opp,
            (const float*)mlp, out, nsplit);
}

// Round 10
// 68.287 us; speedup vs baseline: 1.0393x; 1.0238x over previous
//
#include <hip/hip_runtime.h>
#include <hip/hip_bf16.h>

#define B_ 8
#define S_ 2048
#define E_ 1024
#define H_ 64
#define LOG2E 1.4426950408889634f

typedef __attribute__((ext_vector_type(8))) short short8;
typedef __attribute__((ext_vector_type(4))) short bf16x4;
typedef __attribute__((ext_vector_type(4))) float floatx4;
typedef unsigned int u32;

static __device__ __forceinline__ short f2bf(float f) {
    union { float f; unsigned u; } a; a.f = f;
    unsigned r = a.u + 0x7FFF + ((a.u >> 16) & 1);
    return (short)(r >> 16);
}
static __device__ __forceinline__ float bf2f(short s) {
    union { unsigned u; float f; } a; a.u = ((u32)(unsigned short)s) << 16;
    return a.f;
}
static __device__ __forceinline__ void gl_lds16(const void* g, void* l) {
    __builtin_amdgcn_global_load_lds(
        (const __attribute__((address_space(1))) u32*)(g),
        (__attribute__((address_space(3))) u32*)(l),
        16, 0, 0);
}

// ---------------------------------------------------------------------------
// Kernel 1: weights -> bf16, tiled per K-panel [16][192][64] with XOR chunk
// swizzle pre-applied in global: element (ks,row,col) at
// ks*12288 + row*64 + ((col>>3)^(row&7))*8 + (col&7).
// Two consecutive panels = one BK=128 step for qkv.
// ---------------------------------------------------------------------------
__global__ __launch_bounds__(256) void wprep_kernel(
        const float* __restrict__ wq, const float* __restrict__ wk,
        const float* __restrict__ wv, short* __restrict__ Wt) {
    __shared__ short Ws[64][73];
    int bid = blockIdx.x;            // 48 blocks: m = bid>>4, e-chunk = bid&15
    int m  = bid >> 4;
    int ec = bid & 15;
    const float* src = (m == 0) ? wq : ((m == 1) ? wk : wv);
    int t = threadIdx.x;
    {
        int er = t >> 2;
        int hc = (t & 3) * 16;
        const float* sp = src + (size_t)(ec * 64 + er) * H_ + hc;
        floatx4 v0 = *(const floatx4*)(sp);
        floatx4 v1 = *(const floatx4*)(sp + 4);
        floatx4 v2 = *(const floatx4*)(sp + 8);
        floatx4 v3 = *(const floatx4*)(sp + 12);
#pragma unroll
        for (int j = 0; j < 4; j++) Ws[er][hc + j]      = f2bf(v0[j]);
#pragma unroll
        for (int j = 0; j < 4; j++) Ws[er][hc + 4 + j]  = f2bf(v1[j]);
#pragma unroll
        for (int j = 0; j < 4; j++) Ws[er][hc + 8 + j]  = f2bf(v2[j]);
#pragma unroll
        for (int j = 0; j < 4; j++) Ws[er][hc + 12 + j] = f2bf(v3[j]);
    }
    __syncthreads();
    {
        int h  = t >> 2;
        int eo = (t & 3) * 16;
        int row = m * 64 + h;
        short* obase = Wt + (size_t)ec * 12288 + (size_t)row * 64;
#pragma unroll
        for (int g = 0; g < 2; g++) {
            short8 o;
#pragma unroll
            for (int jj = 0; jj < 8; jj++) o[jj] = Ws[eo + g * 8 + jj][h];
            int chunk = ((eo >> 3) + g) ^ (row & 7);
            *(short8*)(obase + chunk * 8) = o;
        }
    }
}

// ---------------------------------------------------------------------------
// Kernel 2: QKV projection GEMM.  BK=128 (8 steps), BM=64, grid 256
// (1 block/CU), 512 thr = 8 waves as 2-row x 4-col split (wave = 32 rows x
// 48 cols, 6 accs).  Reg-staged write-late depth-1, double-buffered LDS
// (W 2x48 KB + X 2x17 KB = 130 KB).  Halves the barrier-step count.
// ---------------------------------------------------------------------------
struct StageRegs {
    floatx4 x0, x1, x2, x3;
    short8 w0, w1, w2, w3, w4, w5;
};

__global__ __launch_bounds__(512, 2) void qkv_proj_kernel(
        const float* __restrict__ x, const short* __restrict__ Wt,
        short* __restrict__ qb, short* __restrict__ kb, short* __restrict__ vb) {
    __shared__ __align__(16) short Wlds[2][24576];   // 2 x 48 KB (2 panels/step)
    __shared__ __align__(16) short Xlds[2][8704];    // 2 x [64][136] bf16

    int tid  = threadIdx.x;
    int lane = tid & 63;
    int w    = tid >> 6;               // 0..7
    int lrow = lane & 15;
    int lgrp = lane >> 4;

    int wr = w & 1;                    // 32-row half
    int wc = w >> 1;                   // 0..3: 48-col slice
    int rowbase = blockIdx.x * 64;

    // staging maps: x row = tid>>3 (64 rows), 8 chunks of 16 floats (full 128)
    int xr = tid >> 3;
    int xc = tid & 7;
    const float* xgp = x + (size_t)(rowbase + xr) * E_ + xc * 16;
    const short* wgp = Wt + (size_t)tid * 8;

    floatx4 acc0[3], acc1[3];
#pragma unroll
    for (int i = 0; i < 3; i++) {
        acc0[i] = (floatx4){0.f, 0.f, 0.f, 0.f};
        acc1[i] = (floatx4){0.f, 0.f, 0.f, 0.f};
    }

    StageRegs A, B;

#define LOADST(R, S) do {                                                    \
        const float* xn = xgp + (S) * 128;                                   \
        R.x0 = *(const floatx4*)(xn);                                        \
        R.x1 = *(const floatx4*)(xn + 4);                                    \
        R.x2 = *(const floatx4*)(xn + 8);                                    \
        R.x3 = *(const floatx4*)(xn + 12);                                   \
        const short* wn = wgp + (size_t)(S) * 24576;                         \
        R.w0 = *(const short8*)(wn);                                         \
        R.w1 = *(const short8*)(wn + 4096);                                  \
        R.w2 = *(const short8*)(wn + 8192);                                  \
        R.w3 = *(const short8*)(wn + 12288);                                 \
        R.w4 = *(const short8*)(wn + 16384);                                 \
        R.w5 = *(const short8*)(wn + 20480);                                 \
    } while (0)

#define WRITEST(R, BUF) do {                                                 \
        short8 xs0, xs1;                                                     \
        xs0[0] = f2bf(R.x0[0]); xs0[1] = f2bf(R.x0[1]);                      \
        xs0[2] = f2bf(R.x0[2]); xs0[3] = f2bf(R.x0[3]);                      \
        xs0[4] = f2bf(R.x1[0]); xs0[5] = f2bf(R.x1[1]);                      \
        xs0[6] = f2bf(R.x1[2]); xs0[7] = f2bf(R.x1[3]);                      \
        xs1[0] = f2bf(R.x2[0]); xs1[1] = f2bf(R.x2[1]);                      \
        xs1[2] = f2bf(R.x2[2]); xs1[3] = f2bf(R.x2[3]);                      \
        xs1[4] = f2bf(R.x3[0]); xs1[5] = f2bf(R.x3[1]);                      \
        xs1[6] = f2bf(R.x3[2]); xs1[7] = f2bf(R.x3[3]);                      \
        *(short8*)&Xlds[BUF][xr * 136 + xc * 16]     = xs0;                  \
        *(short8*)&Xlds[BUF][xr * 136 + xc * 16 + 8] = xs1;                  \
        short* lw = &Wlds[BUF][tid * 8];                                     \
        *(short8*)(lw)         = R.w0;                                       \
        *(short8*)(lw + 4096)  = R.w1;                                       \
        *(short8*)(lw + 8192)  = R.w2;                                       \
        *(short8*)(lw + 12288) = R.w3;                                       \
        *(short8*)(lw + 16384) = R.w4;                                       \
        *(short8*)(lw + 20480) = R.w5;                                       \
    } while (0)

#define COMPUTE(BUF) do {                                                    \
        const short* xb0 = &Xlds[BUF][(wr * 32 + lrow) * 136 + lgrp * 8];    \
        const short* xb1 = xb0 + 16 * 136;                                   \
        short8 a00 = *(const short8*)(xb0);                                  \
        short8 a01 = *(const short8*)(xb0 + 32);                             \
        short8 a02 = *(const short8*)(xb0 + 64);                             \
        short8 a03 = *(const short8*)(xb0 + 96);                             \
        short8 a10 = *(const short8*)(xb1);                                  \
        short8 a11 = *(const short8*)(xb1 + 32);                             \
        short8 a12 = *(const short8*)(xb1 + 64);                             \
        short8 a13 = *(const short8*)(xb1 + 96);                             \
        _Pragma("unroll")                                                    \
        for (int nf = 0; nf < 3; nf++) {                                     \
            int row = wc * 48 + nf * 16 + lrow;                              \
            int c0  = lgrp ^ (row & 7);                                      \
            const short* wb = &Wlds[BUF][row * 64];                          \
            short8 b0 = *(const short8*)(wb + c0 * 8);                       \
            short8 b1 = *(const short8*)(wb + (c0 ^ 4) * 8);                 \
            short8 b2 = *(const short8*)(wb + 12288 + c0 * 8);               \
            short8 b3 = *(const short8*)(wb + 12288 + (c0 ^ 4) * 8);         \
            acc0[nf] = __builtin_amdgcn_mfma_f32_16x16x32_bf16(a00, b0, acc0[nf], 0, 0, 0); \
            acc0[nf] = __builtin_amdgcn_mfma_f32_16x16x32_bf16(a01, b1, acc0[nf], 0, 0, 0); \
            acc0[nf] = __builtin_amdgcn_mfma_f32_16x16x32_bf16(a02, b2, acc0[nf], 0, 0, 0); \
            acc0[nf] = __builtin_amdgcn_mfma_f32_16x16x32_bf16(a03, b3, acc0[nf], 0, 0, 0); \
            acc1[nf] = __builtin_amdgcn_mfma_f32_16x16x32_bf16(a10, b0, acc1[nf], 0, 0, 0); \
            acc1[nf] = __builtin_amdgcn_mfma_f32_16x16x32_bf16(a11, b1, acc1[nf], 0, 0, 0); \
            acc1[nf] = __builtin_amdgcn_mfma_f32_16x16x32_bf16(a12, b2, acc1[nf], 0, 0, 0); \
            acc1[nf] = __builtin_amdgcn_mfma_f32_16x16x32_bf16(a13, b3, acc1[nf], 0, 0, 0); \
        }                                                                    \
    } while (0)

    // ---- prologue: stage step 0; preload step 1 ----
    LOADST(B, 0);
    WRITEST(B, 0);
    LOADST(A, 1);
    __syncthreads();

    for (int s = 0; s < 8; s += 2) {
        COMPUTE(0);                      // step s (even -> buf0)
        WRITEST(A, 1);                   // stage step s+1
        if (s + 2 < 8) LOADST(B, s + 2);
        __syncthreads();
        COMPUTE(1);                      // step s+1
        if (s + 2 < 8) WRITEST(B, 0);    // stage step s+2
        if (s + 3 < 8) LOADST(A, s + 3);
        __syncthreads();
    }
#undef LOADST
#undef WRITEST
#undef COMPUTE

    // --- epilogue: per-(wave,rowhalf) slabs [16][56] in Wlds[0], then
    //     coalesced short8 stores (1536 chunks / 512 thr = 3 each) ---
    {
#pragma unroll
        for (int nf = 0; nf < 3; nf++)
#pragma unroll
            for (int j = 0; j < 4; j++) {
                Wlds[0][(w * 2 + 0) * 896 + (lgrp * 4 + j) * 56 + nf * 16 + lrow] = f2bf(acc0[nf][j]);
                Wlds[0][(w * 2 + 1) * 896 + (lgrp * 4 + j) * 56 + nf * 16 + lrow] = f2bf(acc1[nf][j]);
            }
        __syncthreads();
#pragma unroll
        for (int k = 0; k < 3; k++) {
            int id   = tid + k * 512;        // 0..1535
            int slab = id / 96;              // 0..15 = w*2 + rh
            int rem  = id % 96;
            int rloc = rem / 6;
            int cm   = rem % 6;
            int w2  = slab >> 1;
            int rh  = slab & 1;
            int swr = w2 & 1;
            int swc = w2 >> 1;
            short8 v = *(const short8*)&Wlds[0][slab * 896 + rloc * 56 + cm * 8];
            int grow = rowbase + swr * 32 + rh * 16 + rloc;
            int gcol = swc * 48 + cm * 8;
            short* dst = (gcol < 64) ? qb : ((gcol < 128) ? kb : vb);
            *(short8*)(dst + (size_t)grow * H_ + (gcol & 63)) = v;
        }
    }
}

// ---------------------------------------------------------------------------
// Kernel 3: causal flash attention, split-KV (unchanged control).
// ---------------------------------------------------------------------------
__global__ __launch_bounds__(256) void attn_kernel(
        const short* __restrict__ qb, const short* __restrict__ kb,
        const short* __restrict__ vb, short* __restrict__ Opart,
        float* __restrict__ ml, int nsplit) {
    __shared__ __align__(16) short Klds[2][4096];   // 2 x 8 KB
    __shared__ __align__(16) short Vt[64][72];      // V^T [h][kv], padded
    __shared__ __align__(16) short Ps[4][16][72];   // per-wave P (and O) tile

    int tid  = threadIdx.x;
    int lane = tid & 63;
    int w    = tid >> 6;
    int lrow = lane & 15;
    int lgrp = lane >> 4;
    int lk   = lgrp * 8;

    int sp = blockIdx.x % nsplit;
    int bq = blockIdx.x / nsplit;
    int qt = bq & 31;
    int b  = bq >> 5;
    int q0 = qt * 64;

    int T = qt + 1;
    int chunk = (T + nsplit - 1) / nsplit;
    int t0 = sp * chunk;
    int t1 = (T < t0 + chunk) ? T : (t0 + chunk);

    size_t mlrow = (size_t)sp * 16384 + (size_t)b * S_ + q0 + w * 16 + lgrp * 4;

    if (t0 >= T) {
        if (lrow == 0) {
#pragma unroll
            for (int j = 0; j < 4; j++) {
                ml[(mlrow + j) * 2 + 0] = -1e30f;
                ml[(mlrow + j) * 2 + 1] = 0.f;
            }
        }
        return;
    }

    const short* kbase = kb + (size_t)b * S_ * H_;
    const short* vbase = vb + (size_t)b * S_ * H_;

    int qrow = q0 + w * 16 + lrow;
    const short* qptr = qb + ((size_t)b * S_ + qrow) * H_;
    short8 qf0 = *(const short8*)(qptr + lk);
    short8 qf1 = *(const short8*)(qptr + 32 + lk);

#define STAGE_K(TT, BUF) do {                                                 \
        int kv0s = (TT) * 64;                                                 \
        _Pragma("unroll")                                                     \
        for (int it = 0; it < 2; it++) {                                      \
            int j = it * 256 + w * 64 + lane;                                 \
            int r = j >> 3; int c = j & 7;                                    \
            const short* pk = kbase + (size_t)(kv0s + r) * H_ +               \
                              ((c ^ (r & 7)) << 3);                           \
            short* lkp = &Klds[BUF][(it * 256 + w * 64) * 8];                 \
            gl_lds16(pk, lkp);                                                \
        } } while (0)

    int kvr = tid >> 2;
    int hs  = (tid & 3) * 16;

    STAGE_K(t0, 0);
    const short* vp0 = vbase + (size_t)(t0 * 64 + kvr) * H_ + hs;
    short8 vr0 = *(const short8*)vp0;
    short8 vr1 = *(const short8*)(vp0 + 8);

    floatx4 O[4];
#pragma unroll
    for (int nf = 0; nf < 4; nf++) O[nf] = (floatx4){0.f, 0.f, 0.f, 0.f};
    float m[4], lsum[4];
#pragma unroll
    for (int j = 0; j < 4; j++) { m[j] = -1e30f; lsum[j] = 0.f; }

    for (int t = t0; t < t1; t++) {
        int cur = (t - t0) & 1;
        int kv0 = t * 64;
        __syncthreads();                 // K(t) staged; Vt/Ps free

        if (t + 1 < t1) STAGE_K(t + 1, cur ^ 1);

        // write V(t) from regs (transposed)
#pragma unroll
        for (int c = 0; c < 8; c++) Vt[hs + c][kvr] = vr0[c];
#pragma unroll
        for (int c = 0; c < 8; c++) Vt[hs + 8 + c][kvr] = vr1[c];

        // prefetch V(t+1)
        if (t + 1 < t1) {
            const short* vp = vbase + (size_t)((t + 1) * 64 + kvr) * H_ + hs;
            vr0 = *(const short8*)vp;
            vr1 = *(const short8*)(vp + 8);
        }

        // --- S = (Q K^T) * scale, K frags from swizzled LDS ---
        floatx4 s[4];
#pragma unroll
        for (int nf = 0; nf < 4; nf++) {
            int r = nf * 16 + lrow;
            int c0 = lgrp ^ (r & 7);
            const short* kp = &Klds[cur][r * 64];
            short8 b0 = *(const short8*)(kp + c0 * 8);
            short8 b1 = *(const short8*)(kp + (c0 ^ 4) * 8);
            floatx4 a = (floatx4){0.f, 0.f, 0.f, 0.f};
            a = __builtin_amdgcn_mfma_f32_16x16x32_bf16(qf0, b0, a, 0, 0, 0);
            a = __builtin_amdgcn_mfma_f32_16x16x32_bf16(qf1, b1, a, 0, 0, 0);
            s[nf] = a;
        }
#pragma unroll
        for (int nf = 0; nf < 4; nf++)
#pragma unroll
            for (int j = 0; j < 4; j++) s[nf][j] *= 0.03125f;

        if (t == qt) {
#pragma unroll
            for (int nf = 0; nf < 4; nf++) {
                int kvidx = kv0 + nf * 16 + lrow;
#pragma unroll
                for (int j = 0; j < 4; j++) {
                    int qidx = q0 + w * 16 + lgrp * 4 + j;
                    if (kvidx > qidx) s[nf][j] = -1e30f;
                }
            }
        }

        float alpha[4];
#pragma unroll
        for (int j = 0; j < 4; j++) {
            float mx = fmaxf(fmaxf(s[0][j], s[1][j]), fmaxf(s[2][j], s[3][j]));
#pragma unroll
            for (int off = 1; off < 16; off <<= 1)
                mx = fmaxf(mx, __shfl_xor(mx, off));
            float mn = fmaxf(m[j], mx);
            alpha[j] = exp2f((m[j] - mn) * LOG2E);
            m[j] = mn;
            float ps = 0.f;
#pragma unroll
            for (int nf = 0; nf < 4; nf++) {
                float p = exp2f((s[nf][j] - mn) * LOG2E);
                s[nf][j] = p;
                ps += p;
            }
#pragma unroll
            for (int off = 1; off < 16; off <<= 1)
                ps += __shfl_xor(ps, off);
            lsum[j] = lsum[j] * alpha[j] + ps;
        }

#pragma unroll
        for (int nf = 0; nf < 4; nf++) {
#pragma unroll
            for (int j = 0; j < 4; j++) {
                Ps[w][lgrp * 4 + j][nf * 16 + lrow] = f2bf(s[nf][j]);
                O[nf][j] *= alpha[j];
            }
        }
        __syncthreads();                 // Ps + Vt visible

        short8 pa0 = *(const short8*)&Ps[w][lrow][lk];
        short8 pa1 = *(const short8*)&Ps[w][lrow][32 + lk];
#pragma unroll
        for (int nf = 0; nf < 4; nf++) {
            short8 vb0 = *(const short8*)&Vt[nf * 16 + lrow][lk];
            short8 vb1 = *(const short8*)&Vt[nf * 16 + lrow][32 + lk];
            O[nf] = __builtin_amdgcn_mfma_f32_16x16x32_bf16(pa0, vb0, O[nf], 0, 0, 0);
            O[nf] = __builtin_amdgcn_mfma_f32_16x16x32_bf16(pa1, vb1, O[nf], 0, 0, 0);
        }
    }
#undef STAGE_K

    // --- epilogue: m,l + transposed coalesced bf16 O stores ---
    if (lrow == 0) {
#pragma unroll
        for (int j = 0; j < 4; j++) {
            ml[(mlrow + j) * 2 + 0] = m[j];
            ml[(mlrow + j) * 2 + 1] = lsum[j];
        }
    }
    __syncthreads();                     // all PV reads of Ps done
#pragma unroll
    for (int nf = 0; nf < 4; nf++)
#pragma unroll
        for (int j = 0; j < 4; j++)
            Ps[w][lgrp * 4 + j][nf * 16 + lrow] = f2bf(O[nf][j]);
    __syncthreads();
    {
        // full 16x64 coverage: 16 rows x 4 lane-chunks x 16 cols
        int row = lane >> 2;
        int c   = lane & 3;
        short8 ov0 = *(const short8*)&Ps[w][row][c * 16];
        short8 ov1 = *(const short8*)&Ps[w][row][c * 16 + 8];
        size_t grow = (size_t)sp * 16384 + (size_t)b * S_ + q0 + w * 16 + row;
        *(short8*)(Opart + grow * H_ + c * 16) = ov0;
        *(short8*)(Opart + grow * H_ + c * 16 + 8) = ov1;
    }
}

// ---------------------------------------------------------------------------
// Kernel 4: combine split partials (bf16 partial O), ACTIVE splits only.
// ---------------------------------------------------------------------------
__global__ __launch_bounds__(256) void combine_kernel(
        const short* __restrict__ Opart, const float* __restrict__ ml,
        float* __restrict__ out, int nsplit) {
    int t = threadIdx.x;
    int row = blockIdx.x * 4 + (t >> 6);   // 0..16383
    int h = t & 63;

    int q = row & (S_ - 1);
    int T = (q >> 6) + 1;
    int chunk = (T + nsplit - 1) / nsplit;
    int nact = (T + chunk - 1) / chunk;

    float M = -1e30f;
    for (int s = 0; s < nact; s++)
        M = fmaxf(M, ml[((size_t)s * 16384 + row) * 2]);

    float L = 0.f, acc = 0.f;
    for (int s = 0; s < nact; s++) {
        float ms = ml[((size_t)s * 16384 + row) * 2];
        float ls = ml[((size_t)s * 16384 + row) * 2 + 1];
        float wgt = exp2f((ms - M) * LOG2E);
        L += wgt * ls;
        acc += wgt * bf2f(Opart[((size_t)s * 16384 + row) * H_ + h]);
    }
    out[(size_t)row * H_ + h] = acc / L;
}

// ---------------------------------------------------------------------------
extern "C" void kernel_launch(void* const* d_in, const int* in_sizes, int n_in,
                              void* d_out, int out_size, void* d_ws, size_t ws_size,
                              hipStream_t stream) {
    const float* x  = (const float*)d_in[0];
    const float* wq = (const float*)d_in[1];
    const float* wk = (const float*)d_in[2];
    const float* wv = (const float*)d_in[3];
    float* out = (float*)d_out;

    char* ws = (char*)d_ws;
    const size_t WT_BYTES  = (size_t)192 * 1024 * 2;            // 384 KB
    const size_t QKV_BYTES = (size_t)B_ * S_ * H_ * 2;          // 2 MB each
    const size_t ML_BYTES  = (size_t)8 * 16384 * 2 * 4;         // 1 MB (8 splits)
    const size_t OP_UNIT   = (size_t)16384 * H_ * 2;            // 2 MB per split (bf16)

    short* Wt = (short*)ws;
    short* qb = (short*)(ws + WT_BYTES);
    short* kb = (short*)(ws + WT_BYTES + QKV_BYTES);
    short* vb = (short*)(ws + WT_BYTES + 2 * QKV_BYTES);
    char*  mlp = ws + WT_BYTES + 3 * QKV_BYTES;
    char*  opp = mlp + ML_BYTES;
    size_t fixed = WT_BYTES + 3 * QKV_BYTES + ML_BYTES;

    int nsplit = 1;
    if (ws_size >= fixed + 8 * OP_UNIT) nsplit = 8;
    else if (ws_size >= fixed + 4 * OP_UNIT) nsplit = 4;
    else if (ws_size >= fixed + 2 * OP_UNIT) nsplit = 2;

    wprep_kernel<<<48, 256, 0, stream>>>(wq, wk, wv, Wt);
    qkv_proj_kernel<<<256, 512, 0, stream>>>(x, Wt, qb, kb, vb);
    attn_kernel<<<8 * 32 * nsplit, 256, 0, stream>>>(qb, kb, vb,
            (short*)opp, (float*)mlp, nsplit);
    combine_kernel<<<4096, 256, 0, stream>>>((const short*)opp,
            (const float*)mlp, out, nsplit);
}

// Round 11
// 63.593 us; speedup vs baseline: 1.1160x; 1.0738x over previous
//
#include <hip/hip_runtime.h>
#include <hip/hip_bf16.h>

#define B_ 8
#define S_ 2048
#define E_ 1024
#define H_ 64
#define LOG2E 1.4426950408889634f

typedef __attribute__((ext_vector_type(8))) short short8;
typedef __attribute__((ext_vector_type(4))) float floatx4;
typedef unsigned int u32;

static __device__ __forceinline__ short f2bf(float f) {
    union { float f; unsigned u; } a; a.f = f;
    unsigned r = a.u + 0x7FFF + ((a.u >> 16) & 1);
    return (short)(r >> 16);
}
static __device__ __forceinline__ float bf2f(short s) {
    union { unsigned u; float f; } a; a.u = ((u32)(unsigned short)s) << 16;
    return a.f;
}
static __device__ __forceinline__ void gl_lds16(const void* g, void* l) {
    __builtin_amdgcn_global_load_lds(
        (const __attribute__((address_space(1))) u32*)(g),
        (__attribute__((address_space(3))) u32*)(l),
        16, 0, 0);
}

// ---------------------------------------------------------------------------
// Kernel 1: weights -> bf16, tiled per K-panel [16][192][64] with XOR chunk
// swizzle pre-applied in global.
// ---------------------------------------------------------------------------
__global__ __launch_bounds__(256) void wprep_kernel(
        const float* __restrict__ wq, const float* __restrict__ wk,
        const float* __restrict__ wv, short* __restrict__ Wt) {
    __shared__ short Ws[64][73];
    int bid = blockIdx.x;
    int m  = bid >> 4;
    int ec = bid & 15;
    const float* src = (m == 0) ? wq : ((m == 1) ? wk : wv);
    int t = threadIdx.x;
    {
        int er = t >> 2;
        int hc = (t & 3) * 16;
        const float* sp = src + (size_t)(ec * 64 + er) * H_ + hc;
        floatx4 v0 = *(const floatx4*)(sp);
        floatx4 v1 = *(const floatx4*)(sp + 4);
        floatx4 v2 = *(const floatx4*)(sp + 8);
        floatx4 v3 = *(const floatx4*)(sp + 12);
#pragma unroll
        for (int j = 0; j < 4; j++) Ws[er][hc + j]      = f2bf(v0[j]);
#pragma unroll
        for (int j = 0; j < 4; j++) Ws[er][hc + 4 + j]  = f2bf(v1[j]);
#pragma unroll
        for (int j = 0; j < 4; j++) Ws[er][hc + 8 + j]  = f2bf(v2[j]);
#pragma unroll
        for (int j = 0; j < 4; j++) Ws[er][hc + 12 + j] = f2bf(v3[j]);
    }
    __syncthreads();
    {
        int h  = t >> 2;
        int eo = (t & 3) * 16;
        int row = m * 64 + h;
        short* obase = Wt + (size_t)ec * 12288 + (size_t)row * 64;
#pragma unroll
        for (int g = 0; g < 2; g++) {
            short8 o;
#pragma unroll
            for (int jj = 0; jj < 8; jj++) o[jj] = Ws[eo + g * 8 + jj][h];
            int chunk = ((eo >> 3) + g) ^ (row & 7);
            *(short8*)(obase + chunk * 8) = o;
        }
    }
}

// ---------------------------------------------------------------------------
// Kernel 2: QKV projection GEMM (unchanged control, r10 version).
// BK=128, BM=64, grid 256, 512 thr = 8 waves (2 row x 4 col).
// ---------------------------------------------------------------------------
struct StageRegs {
    floatx4 x0, x1, x2, x3;
    short8 w0, w1, w2, w3, w4, w5;
};

__global__ __launch_bounds__(512, 2) void qkv_proj_kernel(
        const float* __restrict__ x, const short* __restrict__ Wt,
        short* __restrict__ qb, short* __restrict__ kb, short* __restrict__ vb) {
    __shared__ __align__(16) short Wlds[2][24576];
    __shared__ __align__(16) short Xlds[2][8704];

    int tid  = threadIdx.x;
    int lane = tid & 63;
    int w    = tid >> 6;
    int lrow = lane & 15;
    int lgrp = lane >> 4;

    int wr = w & 1;
    int wc = w >> 1;
    int rowbase = blockIdx.x * 64;

    int xr = tid >> 3;
    int xc = tid & 7;
    const float* xgp = x + (size_t)(rowbase + xr) * E_ + xc * 16;
    const short* wgp = Wt + (size_t)tid * 8;

    floatx4 acc0[3], acc1[3];
#pragma unroll
    for (int i = 0; i < 3; i++) {
        acc0[i] = (floatx4){0.f, 0.f, 0.f, 0.f};
        acc1[i] = (floatx4){0.f, 0.f, 0.f, 0.f};
    }

    StageRegs A, B;

#define LOADST(R, S) do {                                                    \
        const float* xn = xgp + (S) * 128;                                   \
        R.x0 = *(const floatx4*)(xn);                                        \
        R.x1 = *(const floatx4*)(xn + 4);                                    \
        R.x2 = *(const floatx4*)(xn + 8);                                    \
        R.x3 = *(const floatx4*)(xn + 12);                                   \
        const short* wn = wgp + (size_t)(S) * 24576;                         \
        R.w0 = *(const short8*)(wn);                                         \
        R.w1 = *(const short8*)(wn + 4096);                                  \
        R.w2 = *(const short8*)(wn + 8192);                                  \
        R.w3 = *(const short8*)(wn + 12288);                                 \
        R.w4 = *(const short8*)(wn + 16384);                                 \
        R.w5 = *(const short8*)(wn + 20480);                                 \
    } while (0)

#define WRITEST(R, BUF) do {                                                 \
        short8 xs0, xs1;                                                     \
        xs0[0] = f2bf(R.x0[0]); xs0[1] = f2bf(R.x0[1]);                      \
        xs0[2] = f2bf(R.x0[2]); xs0[3] = f2bf(R.x0[3]);                      \
        xs0[4] = f2bf(R.x1[0]); xs0[5] = f2bf(R.x1[1]);                      \
        xs0[6] = f2bf(R.x1[2]); xs0[7] = f2bf(R.x1[3]);                      \
        xs1[0] = f2bf(R.x2[0]); xs1[1] = f2bf(R.x2[1]);                      \
        xs1[2] = f2bf(R.x2[2]); xs1[3] = f2bf(R.x2[3]);                      \
        xs1[4] = f2bf(R.x3[0]); xs1[5] = f2bf(R.x3[1]);                      \
        xs1[6] = f2bf(R.x3[2]); xs1[7] = f2bf(R.x3[3]);                      \
        *(short8*)&Xlds[BUF][xr * 136 + xc * 16]     = xs0;                  \
        *(short8*)&Xlds[BUF][xr * 136 + xc * 16 + 8] = xs1;                  \
        short* lw = &Wlds[BUF][tid * 8];                                     \
        *(short8*)(lw)         = R.w0;                                       \
        *(short8*)(lw + 4096)  = R.w1;                                       \
        *(short8*)(lw + 8192)  = R.w2;                                       \
        *(short8*)(lw + 12288) = R.w3;                                       \
        *(short8*)(lw + 16384) = R.w4;                                       \
        *(short8*)(lw + 20480) = R.w5;                                       \
    } while (0)

#define COMPUTE(BUF) do {                                                    \
        const short* xb0 = &Xlds[BUF][(wr * 32 + lrow) * 136 + lgrp * 8];    \
        const short* xb1 = xb0 + 16 * 136;                                   \
        short8 a00 = *(const short8*)(xb0);                                  \
        short8 a01 = *(const short8*)(xb0 + 32);                             \
        short8 a02 = *(const short8*)(xb0 + 64);                             \
        short8 a03 = *(const short8*)(xb0 + 96);                             \
        short8 a10 = *(const short8*)(xb1);                                  \
        short8 a11 = *(const short8*)(xb1 + 32);                             \
        short8 a12 = *(const short8*)(xb1 + 64);                             \
        short8 a13 = *(const short8*)(xb1 + 96);                             \
        _Pragma("unroll")                                                    \
        for (int nf = 0; nf < 3; nf++) {                                     \
            int row = wc * 48 + nf * 16 + lrow;                              \
            int c0  = lgrp ^ (row & 7);                                      \
            const short* wb = &Wlds[BUF][row * 64];                          \
            short8 b0 = *(const short8*)(wb + c0 * 8);                       \
            short8 b1 = *(const short8*)(wb + (c0 ^ 4) * 8);                 \
            short8 b2 = *(const short8*)(wb + 12288 + c0 * 8);               \
            short8 b3 = *(const short8*)(wb + 12288 + (c0 ^ 4) * 8);         \
            acc0[nf] = __builtin_amdgcn_mfma_f32_16x16x32_bf16(a00, b0, acc0[nf], 0, 0, 0); \
            acc0[nf] = __builtin_amdgcn_mfma_f32_16x16x32_bf16(a01, b1, acc0[nf], 0, 0, 0); \
            acc0[nf] = __builtin_amdgcn_mfma_f32_16x16x32_bf16(a02, b2, acc0[nf], 0, 0, 0); \
            acc0[nf] = __builtin_amdgcn_mfma_f32_16x16x32_bf16(a03, b3, acc0[nf], 0, 0, 0); \
            acc1[nf] = __builtin_amdgcn_mfma_f32_16x16x32_bf16(a10, b0, acc1[nf], 0, 0, 0); \
            acc1[nf] = __builtin_amdgcn_mfma_f32_16x16x32_bf16(a11, b1, acc1[nf], 0, 0, 0); \
            acc1[nf] = __builtin_amdgcn_mfma_f32_16x16x32_bf16(a12, b2, acc1[nf], 0, 0, 0); \
            acc1[nf] = __builtin_amdgcn_mfma_f32_16x16x32_bf16(a13, b3, acc1[nf], 0, 0, 0); \
        }                                                                    \
    } while (0)

    LOADST(B, 0);
    WRITEST(B, 0);
    LOADST(A, 1);
    __syncthreads();

    for (int s = 0; s < 8; s += 2) {
        COMPUTE(0);
        WRITEST(A, 1);
        if (s + 2 < 8) LOADST(B, s + 2);
        __syncthreads();
        COMPUTE(1);
        if (s + 2 < 8) WRITEST(B, 0);
        if (s + 3 < 8) LOADST(A, s + 3);
        __syncthreads();
    }
#undef LOADST
#undef WRITEST
#undef COMPUTE

    {
#pragma unroll
        for (int nf = 0; nf < 3; nf++)
#pragma unroll
            for (int j = 0; j < 4; j++) {
                Wlds[0][(w * 2 + 0) * 896 + (lgrp * 4 + j) * 56 + nf * 16 + lrow] = f2bf(acc0[nf][j]);
                Wlds[0][(w * 2 + 1) * 896 + (lgrp * 4 + j) * 56 + nf * 16 + lrow] = f2bf(acc1[nf][j]);
            }
        __syncthreads();
#pragma unroll
        for (int k = 0; k < 3; k++) {
            int id   = tid + k * 512;
            int slab = id / 96;
            int rem  = id % 96;
            int rloc = rem / 6;
            int cm   = rem % 6;
            int w2  = slab >> 1;
            int rh  = slab & 1;
            int swr = w2 & 1;
            int swc = w2 >> 1;
            short8 v = *(const short8*)&Wlds[0][slab * 896 + rloc * 56 + cm * 8];
            int grow = rowbase + swr * 32 + rh * 16 + rloc;
            int gcol = swc * 48 + cm * 8;
            short* dst = (gcol < 64) ? qb : ((gcol < 128) ? kb : vb);
            *(short8*)(dst + (size_t)grow * H_ + (gcol & 63)) = v;
        }
    }
}

// ---------------------------------------------------------------------------
// Kernel 3: causal flash attention, ADAPTIVE split: each split owns <=8
// KV-tiles (512 KV).  Grid = 8 batches x 80 split-units, no empty blocks.
// Group g = qt>>3: qtile has g+1 splits.  g==0 blocks (qt<=7) cover their
// whole causal range -> write normalized f32 directly to out.  Others write
// bf16 partial O + (m,l); combine merges rows q>=512.
// Big-qt blocks dispatched first (reverse map) to shrink the tail.
// ---------------------------------------------------------------------------
__global__ __launch_bounds__(256) void attn_kernel(
        const short* __restrict__ qb, const short* __restrict__ kb,
        const short* __restrict__ vb, short* __restrict__ Opart,
        float* __restrict__ ml, float* __restrict__ out) {
    __shared__ __align__(16) short Klds[2][4096];   // 2 x 8 KB
    __shared__ __align__(16) short Vt[64][72];      // V^T [h][kv], padded
    __shared__ __align__(16) short Ps[4][16][72];   // per-wave P (and O) tile

    int tid  = threadIdx.x;
    int lane = tid & 63;
    int w    = tid >> 6;
    int lrow = lane & 15;
    int lgrp = lane >> 4;
    int lk   = lgrp * 8;

    // ---- adaptive split mapping (reversed so big blocks launch first) ----
    int idx = 639 - (int)blockIdx.x;
    int b   = idx / 80;
    int r80 = idx - b * 80;
    int g, base;
    if      (r80 < 8)  { g = 0; base = 0;  }
    else if (r80 < 24) { g = 1; base = 8;  }
    else if (r80 < 48) { g = 2; base = 24; }
    else               { g = 3; base = 48; }
    int r    = r80 - base;
    int gp1  = g + 1;
    int qloc = r / gp1;
    int sp   = r - qloc * gp1;
    int qt   = g * 8 + qloc;
    int q0   = qt * 64;
    int T    = qt + 1;
    int t0   = sp * 8;
    int t1   = (T < t0 + 8) ? T : (t0 + 8);

    const short* kbase = kb + (size_t)b * S_ * H_;
    const short* vbase = vb + (size_t)b * S_ * H_;

    int qrow = q0 + w * 16 + lrow;
    const short* qptr = qb + ((size_t)b * S_ + qrow) * H_;
    short8 qf0 = *(const short8*)(qptr + lk);
    short8 qf1 = *(const short8*)(qptr + 32 + lk);

#define STAGE_K(TT, BUF) do {                                                 \
        int kv0s = (TT) * 64;                                                 \
        _Pragma("unroll")                                                     \
        for (int it = 0; it < 2; it++) {                                      \
            int j = it * 256 + w * 64 + lane;                                 \
            int rr = j >> 3; int c = j & 7;                                   \
            const short* pk = kbase + (size_t)(kv0s + rr) * H_ +              \
                              ((c ^ (rr & 7)) << 3);                          \
            short* lkp = &Klds[BUF][(it * 256 + w * 64) * 8];                 \
            gl_lds16(pk, lkp);                                                \
        } } while (0)

    int kvr = tid >> 2;
    int hs  = (tid & 3) * 16;

    STAGE_K(t0, 0);
    const short* vp0 = vbase + (size_t)(t0 * 64 + kvr) * H_ + hs;
    short8 vr0 = *(const short8*)vp0;
    short8 vr1 = *(const short8*)(vp0 + 8);

    floatx4 O[4];
#pragma unroll
    for (int nf = 0; nf < 4; nf++) O[nf] = (floatx4){0.f, 0.f, 0.f, 0.f};
    float m[4], lsum[4];
#pragma unroll
    for (int j = 0; j < 4; j++) { m[j] = -1e30f; lsum[j] = 0.f; }

    for (int t = t0; t < t1; t++) {
        int cur = (t - t0) & 1;
        int kv0 = t * 64;
        __syncthreads();                 // K(t) staged; Vt/Ps free

        if (t + 1 < t1) STAGE_K(t + 1, cur ^ 1);

        // write V(t) from regs (transposed)
#pragma unroll
        for (int c = 0; c < 8; c++) Vt[hs + c][kvr] = vr0[c];
#pragma unroll
        for (int c = 0; c < 8; c++) Vt[hs + 8 + c][kvr] = vr1[c];

        // prefetch V(t+1)
        if (t + 1 < t1) {
            const short* vp = vbase + (size_t)((t + 1) * 64 + kvr) * H_ + hs;
            vr0 = *(const short8*)vp;
            vr1 = *(const short8*)(vp + 8);
        }

        // --- S = (Q K^T) * scale, K frags from swizzled LDS ---
        floatx4 s[4];
#pragma unroll
        for (int nf = 0; nf < 4; nf++) {
            int rr = nf * 16 + lrow;
            int c0 = lgrp ^ (rr & 7);
            const short* kp = &Klds[cur][rr * 64];
            short8 b0 = *(const short8*)(kp + c0 * 8);
            short8 b1 = *(const short8*)(kp + (c0 ^ 4) * 8);
            floatx4 a = (floatx4){0.f, 0.f, 0.f, 0.f};
            a = __builtin_amdgcn_mfma_f32_16x16x32_bf16(qf0, b0, a, 0, 0, 0);
            a = __builtin_amdgcn_mfma_f32_16x16x32_bf16(qf1, b1, a, 0, 0, 0);
            s[nf] = a;
        }
#pragma unroll
        for (int nf = 0; nf < 4; nf++)
#pragma unroll
            for (int j = 0; j < 4; j++) s[nf][j] *= 0.03125f;

        if (t == qt) {
#pragma unroll
            for (int nf = 0; nf < 4; nf++) {
                int kvidx = kv0 + nf * 16 + lrow;
#pragma unroll
                for (int j = 0; j < 4; j++) {
                    int qidx = q0 + w * 16 + lgrp * 4 + j;
                    if (kvidx > qidx) s[nf][j] = -1e30f;
                }
            }
        }

        float alpha[4];
#pragma unroll
        for (int j = 0; j < 4; j++) {
            float mx = fmaxf(fmaxf(s[0][j], s[1][j]), fmaxf(s[2][j], s[3][j]));
#pragma unroll
            for (int off = 1; off < 16; off <<= 1)
                mx = fmaxf(mx, __shfl_xor(mx, off));
            float mn = fmaxf(m[j], mx);
            alpha[j] = exp2f((m[j] - mn) * LOG2E);
            m[j] = mn;
            float ps = 0.f;
#pragma unroll
            for (int nf = 0; nf < 4; nf++) {
                float p = exp2f((s[nf][j] - mn) * LOG2E);
                s[nf][j] = p;
                ps += p;
            }
#pragma unroll
            for (int off = 1; off < 16; off <<= 1)
                ps += __shfl_xor(ps, off);
            lsum[j] = lsum[j] * alpha[j] + ps;
        }

#pragma unroll
        for (int nf = 0; nf < 4; nf++) {
#pragma unroll
            for (int j = 0; j < 4; j++) {
                Ps[w][lgrp * 4 + j][nf * 16 + lrow] = f2bf(s[nf][j]);
                O[nf][j] *= alpha[j];
            }
        }
        __syncthreads();                 // Ps + Vt visible

        short8 pa0 = *(const short8*)&Ps[w][lrow][lk];
        short8 pa1 = *(const short8*)&Ps[w][lrow][32 + lk];
#pragma unroll
        for (int nf = 0; nf < 4; nf++) {
            short8 vb0 = *(const short8*)&Vt[nf * 16 + lrow][lk];
            short8 vb1 = *(const short8*)&Vt[nf * 16 + lrow][32 + lk];
            O[nf] = __builtin_amdgcn_mfma_f32_16x16x32_bf16(pa0, vb0, O[nf], 0, 0, 0);
            O[nf] = __builtin_amdgcn_mfma_f32_16x16x32_bf16(pa1, vb1, O[nf], 0, 0, 0);
        }
    }
#undef STAGE_K

    if (g == 0) {
        // single split covers full causal range: normalized f32 direct to out
#pragma unroll
        for (int nf = 0; nf < 4; nf++)
#pragma unroll
            for (int j = 0; j < 4; j++) {
                size_t grow = (size_t)b * S_ + q0 + w * 16 + lgrp * 4 + j;
                out[grow * H_ + nf * 16 + lrow] = O[nf][j] / lsum[j];
            }
        return;
    }

    // --- partial epilogue: m,l + transposed coalesced bf16 O stores ---
    size_t mlrow = (size_t)sp * 16384 + (size_t)b * S_ + q0 + w * 16 + lgrp * 4;
    if (lrow == 0) {
#pragma unroll
        for (int j = 0; j < 4; j++) {
            ml[(mlrow + j) * 2 + 0] = m[j];
            ml[(mlrow + j) * 2 + 1] = lsum[j];
        }
    }
    __syncthreads();                     // all PV reads of Ps done
#pragma unroll
    for (int nf = 0; nf < 4; nf++)
#pragma unroll
        for (int j = 0; j < 4; j++)
            Ps[w][lgrp * 4 + j][nf * 16 + lrow] = f2bf(O[nf][j]);
    __syncthreads();
    {
        int row = lane >> 2;
        int c   = lane & 3;
        short8 ov0 = *(const short8*)&Ps[w][row][c * 16];
        short8 ov1 = *(const short8*)&Ps[w][row][c * 16 + 8];
        size_t grow = (size_t)sp * 16384 + (size_t)b * S_ + q0 + w * 16 + row;
        *(short8*)(Opart + grow * H_ + c * 16) = ov0;
        *(short8*)(Opart + grow * H_ + c * 16 + 8) = ov1;
    }
}

// ---------------------------------------------------------------------------
// Kernel 4: combine partials for rows q >= 512 only (nact = (q>>9 group)+1).
// 3072 blocks x 256 thr, 4 rows/block.
// ---------------------------------------------------------------------------
__global__ __launch_bounds__(256) void combine_kernel(
        const short* __restrict__ Opart, const float* __restrict__ ml,
        float* __restrict__ out) {
    int t = threadIdx.x;
    int rr = blockIdx.x * 4 + (t >> 6);    // 0..12287
    int h = t & 63;
    int b = rr / 1536;
    int q = 512 + (rr - b * 1536);
    size_t row = (size_t)b * S_ + q;
    int nact = ((q >> 6) >> 3) + 1;        // 2..4

    float M = -1e30f;
    for (int s = 0; s < nact; s++)
        M = fmaxf(M, ml[((size_t)s * 16384 + row) * 2]);

    float L = 0.f, acc = 0.f;
    for (int s = 0; s < nact; s++) {
        float ms = ml[((size_t)s * 16384 + row) * 2];
        float ls = ml[((size_t)s * 16384 + row) * 2 + 1];
        float wgt = exp2f((ms - M) * LOG2E);
        L += wgt * ls;
        acc += wgt * bf2f(Opart[((size_t)s * 16384 + row) * H_ + h]);
    }
    out[row * H_ + h] = acc / L;
}

// ---------------------------------------------------------------------------
extern "C" void kernel_launch(void* const* d_in, const int* in_sizes, int n_in,
                              void* d_out, int out_size, void* d_ws, size_t ws_size,
                              hipStream_t stream) {
    const float* x  = (const float*)d_in[0];
    const float* wq = (const float*)d_in[1];
    const float* wk = (const float*)d_in[2];
    const float* wv = (const float*)d_in[3];
    float* out = (float*)d_out;

    char* ws = (char*)d_ws;
    const size_t WT_BYTES  = (size_t)192 * 1024 * 2;            // 384 KB
    const size_t QKV_BYTES = (size_t)B_ * S_ * H_ * 2;          // 2 MB each
    const size_t ML_BYTES  = (size_t)4 * 16384 * 2 * 4;         // 512 KB (4 splits)

    short* Wt = (short*)ws;
    short* qb = (short*)(ws + WT_BYTES);
    short* kb = (short*)(ws + WT_BYTES + QKV_BYTES);
    short* vb = (short*)(ws + WT_BYTES + 2 * QKV_BYTES);
    char*  mlp = ws + WT_BYTES + 3 * QKV_BYTES;
    char*  opp = mlp + ML_BYTES;                                // 4 x 2 MB bf16

    wprep_kernel<<<48, 256, 0, stream>>>(wq, wk, wv, Wt);
    qkv_proj_kernel<<<256, 512, 0, stream>>>(x, Wt, qb, kb, vb);
    attn_kernel<<<640, 256, 0, stream>>>(qb, kb, vb,
            (short*)opp, (float*)mlp, out);
    combine_kernel<<<3072, 256, 0, stream>>>((const short*)opp,
            (const float*)mlp, out);
}